// Round 2
// baseline (1182.732 us; speedup 1.0000x reference)
//
#include <hip/hip_runtime.h>
#include <hip/hip_bf16.h>

#define N_NODES 50000
#define N_EDGES 800000
#define ETOT (N_EDGES + N_NODES)
#define N_GRAPHS 64
#define HEADS 4
#define IN_CH 128
#define HID 64
#define F1 256  // HEADS*HID
#define OUT_CH 32
#define F2 128  // HEADS*OUT_CH

// ---- CSR build over dst (shared by both GAT layers) ----
__global__ void k_count(const int* __restrict__ ei, int* __restrict__ counts) {
    int e = blockIdx.x * blockDim.x + threadIdx.x;
    if (e >= ETOT) return;
    int dst = (e < N_EDGES) ? ei[N_EDGES + e] : (e - N_EDGES);
    atomicAdd(&counts[dst], 1);
}

__global__ void k_scan(const int* __restrict__ counts, int* __restrict__ offsets) {
    __shared__ int sums[1024];
    int t = threadIdx.x;
    const int chunk = (N_NODES + 1023) / 1024;  // 49
    int s0 = t * chunk;
    int s1 = min(s0 + chunk, N_NODES);
    int acc = 0;
    for (int i = s0; i < s1; i++) acc += counts[i];
    sums[t] = acc;
    __syncthreads();
    for (int off = 1; off < 1024; off <<= 1) {
        int v = (t >= off) ? sums[t - off] : 0;
        __syncthreads();
        sums[t] += v;
        __syncthreads();
    }
    int run = (t == 0) ? 0 : sums[t - 1];
    for (int i = s0; i < s1; i++) { offsets[i] = run; run += counts[i]; }
    if (t == 1023) offsets[N_NODES] = sums[1023];
}

__global__ void k_scatter(const int* __restrict__ ei, const int* __restrict__ offsets,
                          int* __restrict__ cursor, int* __restrict__ csr_src) {
    int e = blockIdx.x * blockDim.x + threadIdx.x;
    if (e >= ETOT) return;
    int src, dst;
    if (e < N_EDGES) { src = ei[e]; dst = ei[N_EDGES + e]; }
    else             { src = dst = e - N_EDGES; }
    int pos = offsets[dst] + atomicAdd(&cursor[dst], 1);
    csr_src[pos] = src;
}

// ---- Row-block GEMM: out[r,col] = sum_k A[r,k] * W[k,col] (all fp32) ----
template <int FIN, int FOUT, int ROWS>
__global__ void k_gemm(const float* __restrict__ A, const float* __restrict__ W,
                       float* __restrict__ out, int nrows) {
    __shared__ float la[ROWS][FIN];
    int r0 = blockIdx.x * ROWS;
    int t = threadIdx.x;  // FOUT threads
    for (int idx = t; idx < ROWS * FIN; idx += FOUT) {
        int rr = idx / FIN, cc = idx - rr * FIN;
        int r = r0 + rr;
        la[rr][cc] = (r < nrows) ? A[(long)r * FIN + cc] : 0.f;
    }
    __syncthreads();
    float acc[ROWS];
#pragma unroll
    for (int rr = 0; rr < ROWS; rr++) acc[rr] = 0.f;
    for (int k = 0; k < FIN; k++) {
        float w = W[k * FOUT + t];
#pragma unroll
        for (int rr = 0; rr < ROWS; rr++) acc[rr] += la[rr][k] * w;
    }
    for (int rr = 0; rr < ROWS; rr++) {
        int r = r0 + rr;
        if (r < nrows) out[(long)r * FOUT + t] = acc[rr];
    }
}

// ---- per-node per-head attention terms s,d ----
template <int H, int C>
__global__ void k_sd(const float* __restrict__ hbuf, const float* __restrict__ asrc,
                     const float* __restrict__ adst,
                     float* __restrict__ s, float* __restrict__ d) {
    int tid = blockIdx.x * blockDim.x + threadIdx.x;
    if (tid >= N_NODES * H) return;
    int n = tid / H, h = tid - n * H;
    const float* row = hbuf + (long)n * (H * C) + h * C;
    float ss = 0.f, dd = 0.f;
    for (int c = 0; c < C; c++) {
        float v = row[c];
        ss += v * asrc[h * C + c];
        dd += v * adst[h * C + c];
    }
    s[tid] = ss; d[tid] = dd;
}

// ---- fused segment-softmax + aggregation + bias + relu (block per node) ----
template <int H, int C>
__global__ void k_agg(const float* __restrict__ hbuf, const float* __restrict__ s,
                      const float* __restrict__ d, const int* __restrict__ offsets,
                      const int* __restrict__ csr_src, const float* __restrict__ bias,
                      float* __restrict__ xout) {
    constexpr int F = H * C;
    constexpr int CHUNK = 512;
    __shared__ int lsrc[CHUNK];
    int n = blockIdx.x;
    int t = threadIdx.x;  // F threads, t = h*C + c
    int h = t / C;
    int beg = offsets[n], end = offsets[n + 1];
    float dn = d[n * H + h];

    float mx = -INFINITY;
    for (int base = beg; base < end; base += CHUNK) {
        int cnt = min(CHUNK, end - base);
        __syncthreads();
        for (int i = t; i < cnt; i += F) lsrc[i] = csr_src[base + i];
        __syncthreads();
        for (int i = 0; i < cnt; i++) {
            float e = s[lsrc[i] * H + h] + dn;
            e = e > 0.f ? e : 0.2f * e;
            mx = fmaxf(mx, e);
        }
    }
    float sumex = 0.f, acc = 0.f;
    for (int base = beg; base < end; base += CHUNK) {
        int cnt = min(CHUNK, end - base);
        __syncthreads();
        for (int i = t; i < cnt; i += F) lsrc[i] = csr_src[base + i];
        __syncthreads();
        for (int i = 0; i < cnt; i++) {
            int sn = lsrc[i];
            float e = s[sn * H + h] + dn;
            e = e > 0.f ? e : 0.2f * e;
            float ex = __expf(e - mx);
            sumex += ex;
            acc += ex * hbuf[(long)sn * F + t];
        }
    }
    float o = acc / (sumex + 1e-16f) + bias[t];
    xout[(long)n * F + t] = fmaxf(o, 0.f);
}

// ---- global mean pool (atomics) ----
__global__ void k_pool(const float* __restrict__ x3, const int* __restrict__ batch,
                       float* __restrict__ pool, float* __restrict__ pcnt) {
    int n = blockIdx.x;
    int t = threadIdx.x;  // F2 threads
    int g = batch[n];
    atomicAdd(&pool[g * F2 + t], x3[(long)n * F2 + t]);
    if (t == 0) atomicAdd(&pcnt[g], 1.0f);
}

// ---- head: mean, logits, softmax ----
__global__ void k_head(const float* __restrict__ pool, const float* __restrict__ pcnt,
                       const float* __restrict__ Wout, const float* __restrict__ bout,
                       float* __restrict__ out) {
    int g = threadIdx.x;
    if (g >= N_GRAPHS) return;
    float cnt = fmaxf(pcnt[g], 1.0f);
    float l0 = bout[0], l1 = bout[1];
    for (int c = 0; c < F2; c++) {
        float p = pool[g * F2 + c] / cnt;
        l0 += p * Wout[c * 2 + 0];
        l1 += p * Wout[c * 2 + 1];
    }
    float m = fmaxf(l0, l1);
    float e0 = __expf(l0 - m), e1 = __expf(l1 - m);
    float inv = 1.f / (e0 + e1);
    out[g * 2 + 0] = e0 * inv;
    out[g * 2 + 1] = e1 * inv;
}

extern "C" void kernel_launch(void* const* d_in, const int* in_sizes, int n_in,
                              void* d_out, int out_size, void* d_ws, size_t ws_size,
                              hipStream_t stream) {
    const float* x     = (const float*)d_in[0];
    const int*   ei    = (const int*)d_in[1];
    const int*   batch = (const int*)d_in[2];
    const float* W1    = (const float*)d_in[3];
    const float* asrc1 = (const float*)d_in[4];
    const float* adst1 = (const float*)d_in[5];
    const float* b1    = (const float*)d_in[6];
    const float* W2    = (const float*)d_in[7];
    const float* asrc2 = (const float*)d_in[8];
    const float* adst2 = (const float*)d_in[9];
    const float* b2    = (const float*)d_in[10];
    const float* Wout  = (const float*)d_in[11];
    const float* bout  = (const float*)d_in[12];

    char* ws = (char*)d_ws;
    size_t off = 0;
    auto alloc = [&](size_t bytes) -> void* {
        void* p = ws + off;
        off += (bytes + 255) / 256 * 256;
        return p;
    };
    float* f_h    = (float*)alloc(sizeof(float) * (size_t)N_NODES * F1);
    float* f_x    = (float*)alloc(sizeof(float) * (size_t)N_NODES * F1);
    float* f_s    = (float*)alloc(sizeof(float) * (size_t)N_NODES * HEADS);
    float* f_d    = (float*)alloc(sizeof(float) * (size_t)N_NODES * HEADS);
    int*   i_cnt  = (int*)alloc(sizeof(int) * (size_t)N_NODES);
    int*   i_off  = (int*)alloc(sizeof(int) * (size_t)(N_NODES + 1));
    int*   i_cur  = (int*)alloc(sizeof(int) * (size_t)N_NODES);
    int*   i_csr  = (int*)alloc(sizeof(int) * (size_t)ETOT);
    float* f_pool = (float*)alloc(sizeof(float) * N_GRAPHS * F2);
    float* f_pcnt = (float*)alloc(sizeof(float) * N_GRAPHS);
    (void)ws_size; (void)in_sizes; (void)n_in; (void)out_size;

    hipMemsetAsync(i_cnt, 0, sizeof(int) * N_NODES, stream);
    hipMemsetAsync(i_cur, 0, sizeof(int) * N_NODES, stream);
    hipMemsetAsync(f_pool, 0, sizeof(float) * N_GRAPHS * F2, stream);
    hipMemsetAsync(f_pcnt, 0, sizeof(float) * N_GRAPHS, stream);

    // CSR over dst (same for both layers)
    k_count<<<(ETOT + 255) / 256, 256, 0, stream>>>(ei, i_cnt);
    k_scan<<<1, 1024, 0, stream>>>(i_cnt, i_off);
    k_scatter<<<(ETOT + 255) / 256, 256, 0, stream>>>(ei, i_off, i_cur, i_csr);

    // Layer 1
    k_gemm<IN_CH, F1, 4><<<(N_NODES + 3) / 4, F1, 0, stream>>>(x, W1, f_h, N_NODES);
    k_sd<HEADS, HID><<<(N_NODES * HEADS + 255) / 256, 256, 0, stream>>>(f_h, asrc1, adst1, f_s, f_d);
    k_agg<HEADS, HID><<<N_NODES, F1, 0, stream>>>(f_h, f_s, f_d, i_off, i_csr, b1, f_x);

    // Layer 2
    k_gemm<F1, F2, 8><<<(N_NODES + 7) / 8, F2, 0, stream>>>(f_x, W2, f_h, N_NODES);
    k_sd<HEADS, OUT_CH><<<(N_NODES * HEADS + 255) / 256, 256, 0, stream>>>(f_h, asrc2, adst2, f_s, f_d);
    k_agg<HEADS, OUT_CH><<<N_NODES, F2, 0, stream>>>(f_h, f_s, f_d, i_off, i_csr, b2, f_x);

    // Pool + head
    k_pool<<<N_NODES, F2, 0, stream>>>(f_x, batch, f_pool, f_pcnt);
    k_head<<<1, 64, 0, stream>>>(f_pool, f_pcnt, Wout, bout, (float*)d_out);
}

// Round 3
// 780.005 us; speedup vs baseline: 1.5163x; 1.5163x over previous
//
#include <hip/hip_runtime.h>
#include <hip/hip_bf16.h>

#define N_NODES 50000
#define N_EDGES 800000
#define ETOT (N_EDGES + N_NODES)
#define N_GRAPHS 64
#define HEADS 4
#define IN_CH 128
#define HID 64
#define F1 256  // HEADS*HID
#define OUT_CH 32
#define F2 128  // HEADS*OUT_CH
#define POOL_SPLITS 16

// ---- CSR build over dst (shared by both GAT layers) ----
__global__ void k_count(const int* __restrict__ ei, int* __restrict__ counts) {
    int e = blockIdx.x * blockDim.x + threadIdx.x;
    if (e >= ETOT) return;
    int dst = (e < N_EDGES) ? ei[N_EDGES + e] : (e - N_EDGES);
    atomicAdd(&counts[dst], 1);
}

__global__ void k_scan(const int* __restrict__ counts, int* __restrict__ offsets) {
    __shared__ int sums[1024];
    int t = threadIdx.x;
    const int chunk = (N_NODES + 1023) / 1024;  // 49
    int s0 = t * chunk;
    int s1 = min(s0 + chunk, N_NODES);
    int acc = 0;
    for (int i = s0; i < s1; i++) acc += counts[i];
    sums[t] = acc;
    __syncthreads();
    for (int off = 1; off < 1024; off <<= 1) {
        int v = (t >= off) ? sums[t - off] : 0;
        __syncthreads();
        sums[t] += v;
        __syncthreads();
    }
    int run = (t == 0) ? 0 : sums[t - 1];
    for (int i = s0; i < s1; i++) { offsets[i] = run; run += counts[i]; }
    if (t == 1023) offsets[N_NODES] = sums[1023];
}

__global__ void k_scatter(const int* __restrict__ ei, const int* __restrict__ offsets,
                          int* __restrict__ cursor, int* __restrict__ csr_src) {
    int e = blockIdx.x * blockDim.x + threadIdx.x;
    if (e >= ETOT) return;
    int src, dst;
    if (e < N_EDGES) { src = ei[e]; dst = ei[N_EDGES + e]; }
    else             { src = dst = e - N_EDGES; }
    int pos = offsets[dst] + atomicAdd(&cursor[dst], 1);
    csr_src[pos] = src;
}

// ---- Row-block GEMM: out[r,col] = sum_k A[r,k] * W[k,col] (all fp32) ----
template <int FIN, int FOUT, int ROWS>
__global__ void k_gemm(const float* __restrict__ A, const float* __restrict__ W,
                       float* __restrict__ out, int nrows) {
    __shared__ float la[ROWS][FIN];
    int r0 = blockIdx.x * ROWS;
    int t = threadIdx.x;  // FOUT threads
    for (int idx = t; idx < ROWS * FIN; idx += FOUT) {
        int rr = idx / FIN, cc = idx - rr * FIN;
        int r = r0 + rr;
        la[rr][cc] = (r < nrows) ? A[(long)r * FIN + cc] : 0.f;
    }
    __syncthreads();
    float acc[ROWS];
#pragma unroll
    for (int rr = 0; rr < ROWS; rr++) acc[rr] = 0.f;
    for (int k = 0; k < FIN; k++) {
        float w = W[k * FOUT + t];
#pragma unroll
        for (int rr = 0; rr < ROWS; rr++) acc[rr] += la[rr][k] * w;
    }
    for (int rr = 0; rr < ROWS; rr++) {
        int r = r0 + rr;
        if (r < nrows) out[(long)r * FOUT + t] = acc[rr];
    }
}

// ---- per-node per-head attention terms s,d ----
template <int H, int C>
__global__ void k_sd(const float* __restrict__ hbuf, const float* __restrict__ asrc,
                     const float* __restrict__ adst,
                     float* __restrict__ s, float* __restrict__ d) {
    int tid = blockIdx.x * blockDim.x + threadIdx.x;
    if (tid >= N_NODES * H) return;
    int n = tid / H, h = tid - n * H;
    const float* row = hbuf + (long)n * (H * C) + h * C;
    float ss = 0.f, dd = 0.f;
    for (int c = 0; c < C; c++) {
        float v = row[c];
        ss += v * asrc[h * C + c];
        dd += v * adst[h * C + c];
    }
    s[tid] = ss; d[tid] = dd;
}

// ---- fused segment-softmax + aggregation + bias + relu (block per node) ----
template <int H, int C>
__global__ void k_agg(const float* __restrict__ hbuf, const float* __restrict__ s,
                      const float* __restrict__ d, const int* __restrict__ offsets,
                      const int* __restrict__ csr_src, const float* __restrict__ bias,
                      float* __restrict__ xout) {
    constexpr int F = H * C;
    constexpr int CHUNK = 512;
    __shared__ int lsrc[CHUNK];
    int n = blockIdx.x;
    int t = threadIdx.x;  // F threads, t = h*C + c
    int h = t / C;
    int beg = offsets[n], end = offsets[n + 1];
    float dn = d[n * H + h];

    float mx = -INFINITY;
    for (int base = beg; base < end; base += CHUNK) {
        int cnt = min(CHUNK, end - base);
        __syncthreads();
        for (int i = t; i < cnt; i += F) lsrc[i] = csr_src[base + i];
        __syncthreads();
        for (int i = 0; i < cnt; i++) {
            float e = s[lsrc[i] * H + h] + dn;
            e = e > 0.f ? e : 0.2f * e;
            mx = fmaxf(mx, e);
        }
    }
    float sumex = 0.f, acc = 0.f;
    for (int base = beg; base < end; base += CHUNK) {
        int cnt = min(CHUNK, end - base);
        __syncthreads();
        for (int i = t; i < cnt; i += F) lsrc[i] = csr_src[base + i];
        __syncthreads();
        for (int i = 0; i < cnt; i++) {
            int sn = lsrc[i];
            float e = s[sn * H + h] + dn;
            e = e > 0.f ? e : 0.2f * e;
            float ex = __expf(e - mx);
            sumex += ex;
            acc += ex * hbuf[(long)sn * F + t];
        }
    }
    float o = acc / (sumex + 1e-16f) + bias[t];
    xout[(long)n * F + t] = fmaxf(o, 0.f);
}

// ---- graph boundaries via binary search on sorted batch ----
__global__ void k_bounds(const int* __restrict__ batch, int* __restrict__ bounds) {
    int g = threadIdx.x;  // 0..64
    if (g > N_GRAPHS) return;
    // lower_bound: first i with batch[i] >= g
    int lo = 0, hi = N_NODES;
    while (lo < hi) {
        int mid = (lo + hi) >> 1;
        if (batch[mid] < g) lo = mid + 1; else hi = mid;
    }
    bounds[g] = lo;
}

// ---- pool partials: block (g,s) sums a contiguous node slice, no atomics ----
__global__ void k_pool_partial(const float* __restrict__ x3, const int* __restrict__ bounds,
                               float* __restrict__ partial) {
    int g = blockIdx.x, s = blockIdx.y;
    int t = threadIdx.x;  // F2 threads
    int n0 = bounds[g], n1 = bounds[g + 1];
    int len = n1 - n0;
    int a = n0 + (int)((long)len * s / POOL_SPLITS);
    int b = n0 + (int)((long)len * (s + 1) / POOL_SPLITS);
    float acc = 0.f;
    for (int n = a; n < b; n++) acc += x3[(long)n * F2 + t];
    partial[((long)g * POOL_SPLITS + s) * F2 + t] = acc;
}

// ---- head: block per graph — reduce partials, mean, logits, softmax ----
__global__ void k_head(const float* __restrict__ partial, const int* __restrict__ bounds,
                       const float* __restrict__ Wout, const float* __restrict__ bout,
                       float* __restrict__ out) {
    __shared__ float red0[F2], red1[F2];
    int g = blockIdx.x;
    int t = threadIdx.x;  // F2 threads
    int cntN = bounds[g + 1] - bounds[g];
    float cnt = fmaxf((float)cntN, 1.0f);
    float sum = 0.f;
    for (int s = 0; s < POOL_SPLITS; s++)
        sum += partial[((long)g * POOL_SPLITS + s) * F2 + t];
    float p = sum / cnt;
    red0[t] = p * Wout[t * 2 + 0];
    red1[t] = p * Wout[t * 2 + 1];
    __syncthreads();
    for (int off = F2 / 2; off > 0; off >>= 1) {
        if (t < off) { red0[t] += red0[t + off]; red1[t] += red1[t + off]; }
        __syncthreads();
    }
    if (t == 0) {
        float l0 = red0[0] + bout[0];
        float l1 = red1[0] + bout[1];
        float m = fmaxf(l0, l1);
        float e0 = __expf(l0 - m), e1 = __expf(l1 - m);
        float inv = 1.f / (e0 + e1);
        out[g * 2 + 0] = e0 * inv;
        out[g * 2 + 1] = e1 * inv;
    }
}

extern "C" void kernel_launch(void* const* d_in, const int* in_sizes, int n_in,
                              void* d_out, int out_size, void* d_ws, size_t ws_size,
                              hipStream_t stream) {
    const float* x     = (const float*)d_in[0];
    const int*   ei    = (const int*)d_in[1];
    const int*   batch = (const int*)d_in[2];
    const float* W1    = (const float*)d_in[3];
    const float* asrc1 = (const float*)d_in[4];
    const float* adst1 = (const float*)d_in[5];
    const float* b1    = (const float*)d_in[6];
    const float* W2    = (const float*)d_in[7];
    const float* asrc2 = (const float*)d_in[8];
    const float* adst2 = (const float*)d_in[9];
    const float* b2    = (const float*)d_in[10];
    const float* Wout  = (const float*)d_in[11];
    const float* bout  = (const float*)d_in[12];

    char* ws = (char*)d_ws;
    size_t off = 0;
    auto alloc = [&](size_t bytes) -> void* {
        void* p = ws + off;
        off += (bytes + 255) / 256 * 256;
        return p;
    };
    float* f_h     = (float*)alloc(sizeof(float) * (size_t)N_NODES * F1);
    float* f_x     = (float*)alloc(sizeof(float) * (size_t)N_NODES * F1);
    float* f_s     = (float*)alloc(sizeof(float) * (size_t)N_NODES * HEADS);
    float* f_d     = (float*)alloc(sizeof(float) * (size_t)N_NODES * HEADS);
    int*   i_cnt   = (int*)alloc(sizeof(int) * (size_t)N_NODES);
    int*   i_off   = (int*)alloc(sizeof(int) * (size_t)(N_NODES + 1));
    int*   i_cur   = (int*)alloc(sizeof(int) * (size_t)N_NODES);
    int*   i_csr   = (int*)alloc(sizeof(int) * (size_t)ETOT);
    int*   i_bnd   = (int*)alloc(sizeof(int) * (size_t)(N_GRAPHS + 1));
    float* f_part  = (float*)alloc(sizeof(float) * (size_t)N_GRAPHS * POOL_SPLITS * F2);
    (void)ws_size; (void)in_sizes; (void)n_in; (void)out_size;

    hipMemsetAsync(i_cnt, 0, sizeof(int) * N_NODES, stream);
    hipMemsetAsync(i_cur, 0, sizeof(int) * N_NODES, stream);

    // CSR over dst (same for both layers)
    k_count<<<(ETOT + 255) / 256, 256, 0, stream>>>(ei, i_cnt);
    k_scan<<<1, 1024, 0, stream>>>(i_cnt, i_off);
    k_scatter<<<(ETOT + 255) / 256, 256, 0, stream>>>(ei, i_off, i_cur, i_csr);

    // Layer 1
    k_gemm<IN_CH, F1, 4><<<(N_NODES + 3) / 4, F1, 0, stream>>>(x, W1, f_h, N_NODES);
    k_sd<HEADS, HID><<<(N_NODES * HEADS + 255) / 256, 256, 0, stream>>>(f_h, asrc1, adst1, f_s, f_d);
    k_agg<HEADS, HID><<<N_NODES, F1, 0, stream>>>(f_h, f_s, f_d, i_off, i_csr, b1, f_x);

    // Layer 2
    k_gemm<F1, F2, 8><<<(N_NODES + 7) / 8, F2, 0, stream>>>(f_x, W2, f_h, N_NODES);
    k_sd<HEADS, OUT_CH><<<(N_NODES * HEADS + 255) / 256, 256, 0, stream>>>(f_h, asrc2, adst2, f_s, f_d);
    k_agg<HEADS, OUT_CH><<<N_NODES, F2, 0, stream>>>(f_h, f_s, f_d, i_off, i_csr, b2, f_x);

    // Pool + head (no atomics: batch is sorted -> contiguous graph ranges)
    k_bounds<<<1, N_GRAPHS + 1, 0, stream>>>(batch, i_bnd);
    dim3 pgrid(N_GRAPHS, POOL_SPLITS);
    k_pool_partial<<<pgrid, F2, 0, stream>>>(f_x, i_bnd, f_part);
    k_head<<<N_GRAPHS, F2, 0, stream>>>(f_part, i_bnd, Wout, bout, (float*)d_out);
}

// Round 4
// 661.633 us; speedup vs baseline: 1.7876x; 1.1789x over previous
//
#include <hip/hip_runtime.h>
#include <hip/hip_bf16.h>

#define N_NODES 50000
#define N_EDGES 800000
#define ETOT (N_EDGES + N_NODES)
#define N_GRAPHS 64
#define HEADS 4
#define IN_CH 128
#define HID 64
#define F1 256  // HEADS*HID
#define OUT_CH 32
#define F2 128  // HEADS*OUT_CH
#define POOL_SPLITS 16

// ---- CSR build over dst (shared by both GAT layers) ----
__global__ void k_count(const int* __restrict__ ei, int* __restrict__ counts) {
    int e = blockIdx.x * blockDim.x + threadIdx.x;
    if (e >= ETOT) return;
    int dst = (e < N_EDGES) ? ei[N_EDGES + e] : (e - N_EDGES);
    atomicAdd(&counts[dst], 1);
}

__global__ void k_scan(const int* __restrict__ counts, int* __restrict__ offsets) {
    __shared__ int sums[1024];
    int t = threadIdx.x;
    const int chunk = (N_NODES + 1023) / 1024;  // 49
    int s0 = t * chunk;
    int s1 = min(s0 + chunk, N_NODES);
    int acc = 0;
    for (int i = s0; i < s1; i++) acc += counts[i];
    sums[t] = acc;
    __syncthreads();
    for (int off = 1; off < 1024; off <<= 1) {
        int v = (t >= off) ? sums[t - off] : 0;
        __syncthreads();
        sums[t] += v;
        __syncthreads();
    }
    int run = (t == 0) ? 0 : sums[t - 1];
    for (int i = s0; i < s1; i++) { offsets[i] = run; run += counts[i]; }
    if (t == 1023) offsets[N_NODES] = sums[1023];
}

__global__ void k_scatter(const int* __restrict__ ei, const int* __restrict__ offsets,
                          int* __restrict__ cursor, int* __restrict__ csr_src) {
    int e = blockIdx.x * blockDim.x + threadIdx.x;
    if (e >= ETOT) return;
    int src, dst;
    if (e < N_EDGES) { src = ei[e]; dst = ei[N_EDGES + e]; }
    else             { src = dst = e - N_EDGES; }
    int pos = offsets[dst] + atomicAdd(&cursor[dst], 1);
    csr_src[pos] = src;
}

// ---- Row-block GEMM: out[r,col] = sum_k A[r,k] * W[k,col] (all fp32) ----
template <int FIN, int FOUT, int ROWS>
__global__ void k_gemm(const float* __restrict__ A, const float* __restrict__ W,
                       float* __restrict__ out, int nrows) {
    __shared__ float la[ROWS][FIN];
    int r0 = blockIdx.x * ROWS;
    int t = threadIdx.x;  // FOUT threads
    for (int idx = t; idx < ROWS * FIN; idx += FOUT) {
        int rr = idx / FIN, cc = idx - rr * FIN;
        int r = r0 + rr;
        la[rr][cc] = (r < nrows) ? A[(long)r * FIN + cc] : 0.f;
    }
    __syncthreads();
    float acc[ROWS];
#pragma unroll
    for (int rr = 0; rr < ROWS; rr++) acc[rr] = 0.f;
    for (int k = 0; k < FIN; k++) {
        float w = W[k * FOUT + t];
#pragma unroll
        for (int rr = 0; rr < ROWS; rr++) acc[rr] += la[rr][k] * w;
    }
    for (int rr = 0; rr < ROWS; rr++) {
        int r = r0 + rr;
        if (r < nrows) out[(long)r * FOUT + t] = acc[rr];
    }
}

// ---- per-node per-head attention terms s,d ----
template <int H, int C>
__global__ void k_sd(const float* __restrict__ hbuf, const float* __restrict__ asrc,
                     const float* __restrict__ adst,
                     float* __restrict__ s, float* __restrict__ d) {
    int tid = blockIdx.x * blockDim.x + threadIdx.x;
    if (tid >= N_NODES * H) return;
    int n = tid / H, h = tid - n * H;
    const float* row = hbuf + (long)n * (H * C) + h * C;
    float ss = 0.f, dd = 0.f;
    for (int c = 0; c < C; c++) {
        float v = row[c];
        ss += v * asrc[h * C + c];
        dd += v * adst[h * C + c];
    }
    s[tid] = ss; d[tid] = dd;
}

// ---- fused segment-softmax + aggregation + bias + relu (block per node) ----
// exp computed once per (edge,head) into LDS; no max pass (|e| <~ 6, exp safe
// in fp32; alpha = exp(e)/sum(exp(e)) is mathematically identical to the
// max-shifted form).
template <int H, int C>
__global__ void k_agg(const float* __restrict__ hbuf, const float* __restrict__ s,
                      const float* __restrict__ d, const int* __restrict__ offsets,
                      const int* __restrict__ csr_src, const float* __restrict__ bias,
                      float* __restrict__ xout) {
    constexpr int F = H * C;
    constexpr int CHUNK = 512;
    __shared__ int lsrc[CHUNK];
    __shared__ float lex[CHUNK * H];
    __shared__ float ldn[H];
    int n = blockIdx.x;
    int t = threadIdx.x;  // F threads, t = h*C + c
    int h = t / C;
    int beg = offsets[n], end = offsets[n + 1];
    if (t < H) ldn[t] = d[n * H + t];

    float sumex = 0.f, acc = 0.f;
    for (int base = beg; base < end; base += CHUNK) {
        int cnt = min(CHUNK, end - base);
        __syncthreads();
        for (int i = t; i < cnt; i += F) lsrc[i] = csr_src[base + i];
        for (int p = t; p < cnt * H; p += F) {
            int i = p / H, hp = p % H;
            int sn = csr_src[base + i];
            float e = s[sn * H + hp] + ldn[hp];
            e = e > 0.f ? e : 0.2f * e;
            lex[p] = __expf(e);
        }
        __syncthreads();
#pragma unroll 4
        for (int i = 0; i < cnt; i++) {
            int sn = lsrc[i];
            float ex = lex[i * H + h];
            sumex += ex;
            acc += ex * hbuf[(long)sn * F + t];
        }
    }
    float o = acc / (sumex + 1e-16f) + bias[t];
    xout[(long)n * F + t] = fmaxf(o, 0.f);
}

// ---- graph boundaries via binary search on sorted batch ----
__global__ void k_bounds(const int* __restrict__ batch, int* __restrict__ bounds) {
    int g = threadIdx.x;  // 0..64
    if (g > N_GRAPHS) return;
    int lo = 0, hi = N_NODES;
    while (lo < hi) {
        int mid = (lo + hi) >> 1;
        if (batch[mid] < g) lo = mid + 1; else hi = mid;
    }
    bounds[g] = lo;
}

// ---- pool partials: block (g,s) sums a contiguous node slice, no atomics ----
__global__ void k_pool_partial(const float* __restrict__ x3, const int* __restrict__ bounds,
                               float* __restrict__ partial) {
    int g = blockIdx.x, s = blockIdx.y;
    int t = threadIdx.x;  // F2 threads
    int n0 = bounds[g], n1 = bounds[g + 1];
    int len = n1 - n0;
    int a = n0 + (int)((long)len * s / POOL_SPLITS);
    int b = n0 + (int)((long)len * (s + 1) / POOL_SPLITS);
    float acc = 0.f;
    for (int n = a; n < b; n++) acc += x3[(long)n * F2 + t];
    partial[((long)g * POOL_SPLITS + s) * F2 + t] = acc;
}

// ---- head: block per graph — reduce partials, mean, logits, softmax ----
__global__ void k_head(const float* __restrict__ partial, const int* __restrict__ bounds,
                       const float* __restrict__ Wout, const float* __restrict__ bout,
                       float* __restrict__ out) {
    __shared__ float red0[F2], red1[F2];
    int g = blockIdx.x;
    int t = threadIdx.x;  // F2 threads
    int cntN = bounds[g + 1] - bounds[g];
    float cnt = fmaxf((float)cntN, 1.0f);
    float sum = 0.f;
    for (int s = 0; s < POOL_SPLITS; s++)
        sum += partial[((long)g * POOL_SPLITS + s) * F2 + t];
    float p = sum / cnt;
    red0[t] = p * Wout[t * 2 + 0];
    red1[t] = p * Wout[t * 2 + 1];
    __syncthreads();
    for (int off = F2 / 2; off > 0; off >>= 1) {
        if (t < off) { red0[t] += red0[t + off]; red1[t] += red1[t + off]; }
        __syncthreads();
    }
    if (t == 0) {
        float l0 = red0[0] + bout[0];
        float l1 = red1[0] + bout[1];
        float m = fmaxf(l0, l1);
        float e0 = __expf(l0 - m), e1 = __expf(l1 - m);
        float inv = 1.f / (e0 + e1);
        out[g * 2 + 0] = e0 * inv;
        out[g * 2 + 1] = e1 * inv;
    }
}

extern "C" void kernel_launch(void* const* d_in, const int* in_sizes, int n_in,
                              void* d_out, int out_size, void* d_ws, size_t ws_size,
                              hipStream_t stream) {
    const float* x     = (const float*)d_in[0];
    const int*   ei    = (const int*)d_in[1];
    const int*   batch = (const int*)d_in[2];
    const float* W1    = (const float*)d_in[3];
    const float* asrc1 = (const float*)d_in[4];
    const float* adst1 = (const float*)d_in[5];
    const float* b1    = (const float*)d_in[6];
    const float* W2    = (const float*)d_in[7];
    const float* asrc2 = (const float*)d_in[8];
    const float* adst2 = (const float*)d_in[9];
    const float* b2    = (const float*)d_in[10];
    const float* Wout  = (const float*)d_in[11];
    const float* bout  = (const float*)d_in[12];

    char* ws = (char*)d_ws;
    size_t off = 0;
    auto alloc = [&](size_t bytes) -> void* {
        void* p = ws + off;
        off += (bytes + 255) / 256 * 256;
        return p;
    };
    float* f_h     = (float*)alloc(sizeof(float) * (size_t)N_NODES * F1);
    float* f_x     = (float*)alloc(sizeof(float) * (size_t)N_NODES * F1);
    float* f_s     = (float*)alloc(sizeof(float) * (size_t)N_NODES * HEADS);
    float* f_d     = (float*)alloc(sizeof(float) * (size_t)N_NODES * HEADS);
    int*   i_cnt   = (int*)alloc(sizeof(int) * (size_t)N_NODES);
    int*   i_off   = (int*)alloc(sizeof(int) * (size_t)(N_NODES + 1));
    int*   i_cur   = (int*)alloc(sizeof(int) * (size_t)N_NODES);
    int*   i_csr   = (int*)alloc(sizeof(int) * (size_t)ETOT);
    int*   i_bnd   = (int*)alloc(sizeof(int) * (size_t)(N_GRAPHS + 1));
    float* f_part  = (float*)alloc(sizeof(float) * (size_t)N_GRAPHS * POOL_SPLITS * F2);
    (void)ws_size; (void)in_sizes; (void)n_in; (void)out_size;

    hipMemsetAsync(i_cnt, 0, sizeof(int) * N_NODES, stream);
    hipMemsetAsync(i_cur, 0, sizeof(int) * N_NODES, stream);

    // CSR over dst (same for both layers)
    k_count<<<(ETOT + 255) / 256, 256, 0, stream>>>(ei, i_cnt);
    k_scan<<<1, 1024, 0, stream>>>(i_cnt, i_off);
    k_scatter<<<(ETOT + 255) / 256, 256, 0, stream>>>(ei, i_off, i_cur, i_csr);

    // Layer 1
    k_gemm<IN_CH, F1, 4><<<(N_NODES + 3) / 4, F1, 0, stream>>>(x, W1, f_h, N_NODES);
    k_sd<HEADS, HID><<<(N_NODES * HEADS + 255) / 256, 256, 0, stream>>>(f_h, asrc1, adst1, f_s, f_d);
    k_agg<HEADS, HID><<<N_NODES, F1, 0, stream>>>(f_h, f_s, f_d, i_off, i_csr, b1, f_x);

    // Layer 2
    k_gemm<F1, F2, 8><<<(N_NODES + 7) / 8, F2, 0, stream>>>(f_x, W2, f_h, N_NODES);
    k_sd<HEADS, OUT_CH><<<(N_NODES * HEADS + 255) / 256, 256, 0, stream>>>(f_h, asrc2, adst2, f_s, f_d);
    k_agg<HEADS, OUT_CH><<<N_NODES, F2, 0, stream>>>(f_h, f_s, f_d, i_off, i_csr, b2, f_x);

    // Pool + head (no atomics: batch is sorted -> contiguous graph ranges)
    k_bounds<<<1, N_GRAPHS + 1, 0, stream>>>(batch, i_bnd);
    dim3 pgrid(N_GRAPHS, POOL_SPLITS);
    k_pool_partial<<<pgrid, F2, 0, stream>>>(f_x, i_bnd, f_part);
    k_head<<<N_GRAPHS, F2, 0, stream>>>(f_part, i_bnd, Wout, bout, (float*)d_out);
}

// Round 5
// 567.293 us; speedup vs baseline: 2.0849x; 1.1663x over previous
//
#include <hip/hip_runtime.h>
#include <hip/hip_bf16.h>

#define N_NODES 50000
#define N_EDGES 800000
#define ETOT (N_EDGES + N_NODES)
#define N_GRAPHS 64
#define HEADS 4
#define IN_CH 128
#define HID 64
#define F1 256  // HEADS*HID
#define OUT_CH 32
#define F2 128  // HEADS*OUT_CH
#define POOL_SPLITS 16

typedef unsigned short ushortT;
typedef unsigned int uintT;

__device__ __forceinline__ ushortT f2bf(float f) {
    union { float f; unsigned int i; } v; v.f = f;
    unsigned int x = v.i;
    unsigned int r = (x + 0x7fffu + ((x >> 16) & 1u)) >> 16;  // RNE
    return (ushortT)r;
}
__device__ __forceinline__ float bf_lo(uintT w) {  // low ushort -> float
    union { unsigned int i; float f; } v; v.i = w << 16; return v.f;
}
__device__ __forceinline__ float bf_hi(uintT w) {  // high ushort -> float
    union { unsigned int i; float f; } v; v.i = w & 0xffff0000u; return v.f;
}

// ---- CSR build over dst (shared by both GAT layers) ----
__global__ void k_count(const int* __restrict__ ei, int* __restrict__ counts) {
    int e = blockIdx.x * blockDim.x + threadIdx.x;
    if (e >= ETOT) return;
    int dst = (e < N_EDGES) ? ei[N_EDGES + e] : (e - N_EDGES);
    atomicAdd(&counts[dst], 1);
}

__global__ void k_scan(const int* __restrict__ counts, int* __restrict__ offsets) {
    __shared__ int sums[1024];
    int t = threadIdx.x;
    const int chunk = (N_NODES + 1023) / 1024;  // 49
    int s0 = t * chunk;
    int s1 = min(s0 + chunk, N_NODES);
    int acc = 0;
    for (int i = s0; i < s1; i++) acc += counts[i];
    sums[t] = acc;
    __syncthreads();
    for (int off = 1; off < 1024; off <<= 1) {
        int v = (t >= off) ? sums[t - off] : 0;
        __syncthreads();
        sums[t] += v;
        __syncthreads();
    }
    int run = (t == 0) ? 0 : sums[t - 1];
    for (int i = s0; i < s1; i++) { offsets[i] = run; run += counts[i]; }
    if (t == 1023) offsets[N_NODES] = sums[1023];
}

__global__ void k_scatter(const int* __restrict__ ei, const int* __restrict__ offsets,
                          int* __restrict__ cursor, int* __restrict__ csr_src) {
    int e = blockIdx.x * blockDim.x + threadIdx.x;
    if (e >= ETOT) return;
    int src, dst;
    if (e < N_EDGES) { src = ei[e]; dst = ei[N_EDGES + e]; }
    else             { src = dst = e - N_EDGES; }
    int pos = offsets[dst] + atomicAdd(&cursor[dst], 1);
    csr_src[pos] = src;
}

// ---- Row-block GEMM: out[r,col] = sum_k A[r,k]*W[k,col]; fp32 in, bf16 out ----
template <int FIN, int FOUT, int ROWS>
__global__ void k_gemm(const float* __restrict__ A, const float* __restrict__ W,
                       ushortT* __restrict__ out, int nrows) {
    __shared__ float la[ROWS][FIN];
    int r0 = blockIdx.x * ROWS;
    int t = threadIdx.x;  // FOUT threads
    for (int idx = t; idx < ROWS * FIN; idx += FOUT) {
        int rr = idx / FIN, cc = idx - rr * FIN;
        int r = r0 + rr;
        la[rr][cc] = (r < nrows) ? A[(long)r * FIN + cc] : 0.f;
    }
    __syncthreads();
    float acc[ROWS];
#pragma unroll
    for (int rr = 0; rr < ROWS; rr++) acc[rr] = 0.f;
    for (int k = 0; k < FIN; k++) {
        float w = W[k * FOUT + t];
#pragma unroll
        for (int rr = 0; rr < ROWS; rr++) acc[rr] += la[rr][k] * w;
    }
    for (int rr = 0; rr < ROWS; rr++) {
        int r = r0 + rr;
        if (r < nrows) out[(long)r * FOUT + t] = f2bf(acc[rr]);
    }
}

// ---- per-node per-head attention terms s,d (bf16 h input) ----
template <int H, int C>
__global__ void k_sd(const ushortT* __restrict__ hb, const float* __restrict__ asrc,
                     const float* __restrict__ adst,
                     float* __restrict__ s, float* __restrict__ d) {
    int tid = blockIdx.x * blockDim.x + threadIdx.x;
    if (tid >= N_NODES * H) return;
    int n = tid / H, h = tid - n * H;
    const uintT* row = (const uintT*)(hb + (long)n * (H * C) + h * C);
    float ss = 0.f, dd = 0.f;
#pragma unroll 4
    for (int c2 = 0; c2 < C / 2; c2++) {
        uintT w = row[c2];
        float v0 = bf_lo(w), v1 = bf_hi(w);
        ss += v0 * asrc[h * C + 2 * c2] + v1 * asrc[h * C + 2 * c2 + 1];
        dd += v0 * adst[h * C + 2 * c2] + v1 * adst[h * C + 2 * c2 + 1];
    }
    s[tid] = ss; d[tid] = dd;
}

// ---- fused segment-softmax + aggregation + bias + relu ----
// One node per block, F/2 threads; thread t owns features (2t, 2t+1) via one
// dword (2xbf16) gather per edge. exp computed once per (edge,head) into LDS.
// No max pass: |e| <~ 6 so exp is fp32-safe; alpha identical mathematically.
template <int H, int C>
__global__ void k_agg(const ushortT* __restrict__ hb, const float* __restrict__ s,
                      const float* __restrict__ d, const int* __restrict__ offsets,
                      const int* __restrict__ csr_src, const float* __restrict__ bias,
                      float* __restrict__ xout) {
    static_assert(H == 4, "H=4 assumed for shift tricks");
    constexpr int F = H * C;
    constexpr int TPN = F / 2;   // threads per node
    constexpr int CHUNK = 256;
    __shared__ int lsrc[CHUNK];
    __shared__ float lex[CHUNK * H];
    __shared__ float ldn[H];
    int n = blockIdx.x;
    int t = threadIdx.x;          // 0..TPN-1
    int h = t / (C / 2);          // head of features 2t,2t+1
    int beg = offsets[n], end = offsets[n + 1];
    if (t < H) ldn[t] = d[n * H + t];

    const uintT* hbw = (const uintT*)hb;  // 2 bf16 per dword, row stride TPN dwords
    float sumex = 0.f, acc0 = 0.f, acc1 = 0.f;
    for (int base = beg; base < end; base += CHUNK) {
        int cnt = min(CHUNK, end - base);
        __syncthreads();
        for (int i = t; i < cnt; i += TPN) lsrc[i] = csr_src[base + i];
        for (int p = t; p < cnt * H; p += TPN) {
            int i = p >> 2;       // p / H
            int hp = p & 3;       // p % H
            int sn = csr_src[base + i];
            float e = s[sn * H + hp] + ldn[hp];
            e = e > 0.f ? e : 0.2f * e;
            lex[p] = __expf(e);
        }
        __syncthreads();
#pragma unroll 4
        for (int i = 0; i < cnt; i++) {
            int sn = lsrc[i];
            float ex = lex[i * H + h];
            sumex += ex;
            uintT w = hbw[(long)sn * TPN + t];
            acc0 += ex * bf_lo(w);
            acc1 += ex * bf_hi(w);
        }
    }
    float inv = 1.f / (sumex + 1e-16f);
    float o0 = acc0 * inv + bias[2 * t];
    float o1 = acc1 * inv + bias[2 * t + 1];
    xout[(long)n * F + 2 * t]     = fmaxf(o0, 0.f);
    xout[(long)n * F + 2 * t + 1] = fmaxf(o1, 0.f);
}

// ---- graph boundaries via binary search on sorted batch ----
__global__ void k_bounds(const int* __restrict__ batch, int* __restrict__ bounds) {
    int g = threadIdx.x;  // 0..64
    if (g > N_GRAPHS) return;
    int lo = 0, hi = N_NODES;
    while (lo < hi) {
        int mid = (lo + hi) >> 1;
        if (batch[mid] < g) lo = mid + 1; else hi = mid;
    }
    bounds[g] = lo;
}

// ---- pool partials: block (g,s) sums a contiguous node slice, no atomics ----
__global__ void k_pool_partial(const float* __restrict__ x3, const int* __restrict__ bounds,
                               float* __restrict__ partial) {
    int g = blockIdx.x, s = blockIdx.y;
    int t = threadIdx.x;  // F2 threads
    int n0 = bounds[g], n1 = bounds[g + 1];
    int len = n1 - n0;
    int a = n0 + (int)((long)len * s / POOL_SPLITS);
    int b = n0 + (int)((long)len * (s + 1) / POOL_SPLITS);
    float acc = 0.f;
    for (int n = a; n < b; n++) acc += x3[(long)n * F2 + t];
    partial[((long)g * POOL_SPLITS + s) * F2 + t] = acc;
}

// ---- head: block per graph — reduce partials, mean, logits, softmax ----
__global__ void k_head(const float* __restrict__ partial, const int* __restrict__ bounds,
                       const float* __restrict__ Wout, const float* __restrict__ bout,
                       float* __restrict__ out) {
    __shared__ float red0[F2], red1[F2];
    int g = blockIdx.x;
    int t = threadIdx.x;  // F2 threads
    int cntN = bounds[g + 1] - bounds[g];
    float cnt = fmaxf((float)cntN, 1.0f);
    float sum = 0.f;
    for (int s = 0; s < POOL_SPLITS; s++)
        sum += partial[((long)g * POOL_SPLITS + s) * F2 + t];
    float p = sum / cnt;
    red0[t] = p * Wout[t * 2 + 0];
    red1[t] = p * Wout[t * 2 + 1];
    __syncthreads();
    for (int off = F2 / 2; off > 0; off >>= 1) {
        if (t < off) { red0[t] += red0[t + off]; red1[t] += red1[t + off]; }
        __syncthreads();
    }
    if (t == 0) {
        float l0 = red0[0] + bout[0];
        float l1 = red1[0] + bout[1];
        float m = fmaxf(l0, l1);
        float e0 = __expf(l0 - m), e1 = __expf(l1 - m);
        float inv = 1.f / (e0 + e1);
        out[g * 2 + 0] = e0 * inv;
        out[g * 2 + 1] = e1 * inv;
    }
}

extern "C" void kernel_launch(void* const* d_in, const int* in_sizes, int n_in,
                              void* d_out, int out_size, void* d_ws, size_t ws_size,
                              hipStream_t stream) {
    const float* x     = (const float*)d_in[0];
    const int*   ei    = (const int*)d_in[1];
    const int*   batch = (const int*)d_in[2];
    const float* W1    = (const float*)d_in[3];
    const float* asrc1 = (const float*)d_in[4];
    const float* adst1 = (const float*)d_in[5];
    const float* b1    = (const float*)d_in[6];
    const float* W2    = (const float*)d_in[7];
    const float* asrc2 = (const float*)d_in[8];
    const float* adst2 = (const float*)d_in[9];
    const float* b2    = (const float*)d_in[10];
    const float* Wout  = (const float*)d_in[11];
    const float* bout  = (const float*)d_in[12];

    char* ws = (char*)d_ws;
    size_t off = 0;
    auto alloc = [&](size_t bytes) -> void* {
        void* p = ws + off;
        off += (bytes + 255) / 256 * 256;
        return p;
    };
    ushortT* u_h   = (ushortT*)alloc(sizeof(ushortT) * (size_t)N_NODES * F1);  // bf16 h (both layers)
    float* f_x     = (float*)alloc(sizeof(float) * (size_t)N_NODES * F1);      // fp32 agg out (both layers)
    float* f_s     = (float*)alloc(sizeof(float) * (size_t)N_NODES * HEADS);
    float* f_d     = (float*)alloc(sizeof(float) * (size_t)N_NODES * HEADS);
    int*   i_cnt   = (int*)alloc(sizeof(int) * (size_t)N_NODES);
    int*   i_off   = (int*)alloc(sizeof(int) * (size_t)(N_NODES + 1));
    int*   i_cur   = (int*)alloc(sizeof(int) * (size_t)N_NODES);
    int*   i_csr   = (int*)alloc(sizeof(int) * (size_t)ETOT);
    int*   i_bnd   = (int*)alloc(sizeof(int) * (size_t)(N_GRAPHS + 1));
    float* f_part  = (float*)alloc(sizeof(float) * (size_t)N_GRAPHS * POOL_SPLITS * F2);
    (void)ws_size; (void)in_sizes; (void)n_in; (void)out_size;

    hipMemsetAsync(i_cnt, 0, sizeof(int) * N_NODES, stream);
    hipMemsetAsync(i_cur, 0, sizeof(int) * N_NODES, stream);

    // CSR over dst (same for both layers)
    k_count<<<(ETOT + 255) / 256, 256, 0, stream>>>(ei, i_cnt);
    k_scan<<<1, 1024, 0, stream>>>(i_cnt, i_off);
    k_scatter<<<(ETOT + 255) / 256, 256, 0, stream>>>(ei, i_off, i_cur, i_csr);

    // Layer 1
    k_gemm<IN_CH, F1, 4><<<(N_NODES + 3) / 4, F1, 0, stream>>>(x, W1, u_h, N_NODES);
    k_sd<HEADS, HID><<<(N_NODES * HEADS + 255) / 256, 256, 0, stream>>>(u_h, asrc1, adst1, f_s, f_d);
    k_agg<HEADS, HID><<<N_NODES, F1 / 2, 0, stream>>>(u_h, f_s, f_d, i_off, i_csr, b1, f_x);

    // Layer 2
    k_gemm<F1, F2, 8><<<(N_NODES + 7) / 8, F2, 0, stream>>>(f_x, W2, u_h, N_NODES);
    k_sd<HEADS, OUT_CH><<<(N_NODES * HEADS + 255) / 256, 256, 0, stream>>>(u_h, asrc2, adst2, f_s, f_d);
    k_agg<HEADS, OUT_CH><<<N_NODES, F2 / 2, 0, stream>>>(u_h, f_s, f_d, i_off, i_csr, b2, f_x);

    // Pool + head (no atomics: batch is sorted -> contiguous graph ranges)
    k_bounds<<<1, N_GRAPHS + 1, 0, stream>>>(batch, i_bnd);
    dim3 pgrid(N_GRAPHS, POOL_SPLITS);
    k_pool_partial<<<pgrid, F2, 0, stream>>>(f_x, i_bnd, f_part);
    k_head<<<N_GRAPHS, F2, 0, stream>>>(f_part, i_bnd, Wout, bout, (float*)d_out);
}

// Round 6
// 456.052 us; speedup vs baseline: 2.5934x; 1.2439x over previous
//
#include <hip/hip_runtime.h>
#include <hip/hip_bf16.h>

#define N_NODES 50000
#define N_EDGES 800000
#define ETOT (N_EDGES + N_NODES)
#define N_GRAPHS 64
#define HEADS 4
#define IN_CH 128
#define HID 64
#define F1 256  // HEADS*HID
#define OUT_CH 32
#define F2 128  // HEADS*OUT_CH
#define POOL_SPLITS 16

typedef unsigned short ushortT;
typedef unsigned int uintT;
typedef short v8s __attribute__((ext_vector_type(8)));
typedef float v4f __attribute__((ext_vector_type(4)));

__device__ __forceinline__ ushortT f2bf(float f) {
    union { float f; unsigned int i; } v; v.f = f;
    unsigned int x = v.i;
    unsigned int r = (x + 0x7fffu + ((x >> 16) & 1u)) >> 16;  // RNE
    return (ushortT)r;
}
__device__ __forceinline__ float bf_lo(uintT w) {
    union { unsigned int i; float f; } v; v.i = w << 16; return v.f;
}
__device__ __forceinline__ float bf_hi(uintT w) {
    union { unsigned int i; float f; } v; v.i = w & 0xffff0000u; return v.f;
}

// ---- CSR build over dst (shared by both GAT layers) ----
__global__ void k_count(const int* __restrict__ ei, int* __restrict__ counts) {
    int e = blockIdx.x * blockDim.x + threadIdx.x;
    if (e >= ETOT) return;
    int dst = (e < N_EDGES) ? ei[N_EDGES + e] : (e - N_EDGES);
    atomicAdd(&counts[dst], 1);
}

__global__ void k_scan(const int* __restrict__ counts, int* __restrict__ offsets) {
    __shared__ int sums[1024];
    int t = threadIdx.x;
    const int chunk = (N_NODES + 1023) / 1024;  // 49
    int s0 = t * chunk;
    int s1 = min(s0 + chunk, N_NODES);
    int acc = 0;
    for (int i = s0; i < s1; i++) acc += counts[i];
    sums[t] = acc;
    __syncthreads();
    for (int off = 1; off < 1024; off <<= 1) {
        int v = (t >= off) ? sums[t - off] : 0;
        __syncthreads();
        sums[t] += v;
        __syncthreads();
    }
    int run = (t == 0) ? 0 : sums[t - 1];
    for (int i = s0; i < s1; i++) { offsets[i] = run; run += counts[i]; }
    if (t == 1023) offsets[N_NODES] = sums[1023];
}

__global__ void k_scatter(const int* __restrict__ ei, const int* __restrict__ offsets,
                          int* __restrict__ cursor, int* __restrict__ csr_src) {
    int e = blockIdx.x * blockDim.x + threadIdx.x;
    if (e >= ETOT) return;
    int src, dst;
    if (e < N_EDGES) { src = ei[e]; dst = ei[N_EDGES + e]; }
    else             { src = dst = e - N_EDGES; }
    int pos = offsets[dst] + atomicAdd(&cursor[dst], 1);
    csr_src[pos] = src;
}

// ---- pack W (fp32 [K][N]) into bf16 B-fragment order for 16x16x32 MFMA ----
// packed[((nt*KC+kc)*64 + lane)*8 + j] = bf16( W[kc*32 + (lane>>4)*8 + j][nt*16 + (lane&15)] )
template <int FIN, int FOUT>
__global__ void k_packW(const float* __restrict__ W, ushortT* __restrict__ pW) {
    constexpr int KC = FIN / 32;
    int tid = blockIdx.x * blockDim.x + threadIdx.x;  // FIN*FOUT/8 threads
    if (tid >= FIN * FOUT / 8) return;
    int lane = tid & 63;
    int g = tid >> 6;
    int kc = g % KC, nt = g / KC;
    int n = nt * 16 + (lane & 15);
    int kbase = kc * 32 + (lane >> 4) * 8;
    union { uint4 q; ushortT u[8]; } pk;
#pragma unroll
    for (int j = 0; j < 8; j++) pk.u[j] = f2bf(W[(kbase + j) * FOUT + n]);
    ((uint4*)pW)[tid] = pk.q;
}

// ---- MFMA GEMM: out[r][n] = sum_k A[r][k]*W[k][n], bf16 out ----
// Block: 256 thr / 4 waves; W (packed bf16) staged to LDS; wave = 16-row strip.
template <int FIN, int FOUT, bool ABF16>
__global__ __launch_bounds__(256) void k_gemm_mfma(const void* __restrict__ A,
                                                   const uint4* __restrict__ Wp,
                                                   ushortT* __restrict__ out, int nrows) {
    constexpr int KC = FIN / 32;
    constexpr int NT = FOUT / 16;
    __shared__ uintT lW[FIN * FOUT / 2];  // 64 KB
    int tid = threadIdx.x;
    uint4* lW4 = (uint4*)lW;
    for (int i = tid; i < FIN * FOUT * 2 / 16; i += 256) lW4[i] = Wp[i];
    __syncthreads();

    int wave = tid >> 6, lane = tid & 63;
    long row0 = (long)blockIdx.x * 64 + wave * 16;
    if (row0 >= nrows) return;  // wave-uniform (nrows % 16 == 0)
    int m = lane & 15, b = lane >> 4;

    v8s afrag[KC];
    if (ABF16) {
        const ushortT* Ab = (const ushortT*)A;
#pragma unroll
        for (int kc = 0; kc < KC; kc++) {
            union { v8s v; uint4 q; } u;
            u.q = *(const uint4*)(Ab + (row0 + m) * FIN + kc * 32 + b * 8);
            afrag[kc] = u.v;
        }
    } else {
        const float* Af = (const float*)A;
#pragma unroll
        for (int kc = 0; kc < KC; kc++) {
            union { v8s v; ushortT u[8]; } u;
            const float* p = Af + (row0 + m) * FIN + kc * 32 + b * 8;
#pragma unroll
            for (int j = 0; j < 8; j++) u.u[j] = f2bf(p[j]);
            afrag[kc] = u.v;
        }
    }

    const ushortT* lWs = (const ushortT*)lW;
#pragma unroll
    for (int nt = 0; nt < NT; nt++) {
        v4f c = {0.f, 0.f, 0.f, 0.f};
#pragma unroll
        for (int kc = 0; kc < KC; kc++) {
            union { v8s v; uint4 q; } bu;
            bu.q = *(const uint4*)(lWs + ((nt * KC + kc) * 64 + lane) * 8);
            c = __builtin_amdgcn_mfma_f32_16x16x32_bf16(afrag[kc], bu.v, c, 0, 0, 0);
        }
        // C/D: col = lane&15, row = (lane>>4)*4 + reg   [measured m89/m91]
        long r = row0 + b * 4;
        int col = nt * 16 + m;
#pragma unroll
        for (int reg = 0; reg < 4; reg++)
            out[(r + reg) * FOUT + col] = f2bf(c[reg]);
    }
}

// ---- per-node per-head attention terms s,d (bf16 h input) ----
template <int H, int C>
__global__ void k_sd(const ushortT* __restrict__ hb, const float* __restrict__ asrc,
                     const float* __restrict__ adst,
                     float* __restrict__ s, float* __restrict__ d) {
    int tid = blockIdx.x * blockDim.x + threadIdx.x;
    if (tid >= N_NODES * H) return;
    int n = tid / H, h = tid - n * H;
    const uintT* row = (const uintT*)(hb + (long)n * (H * C) + h * C);
    float ss = 0.f, dd = 0.f;
#pragma unroll 4
    for (int c2 = 0; c2 < C / 2; c2++) {
        uintT w = row[c2];
        float v0 = bf_lo(w), v1 = bf_hi(w);
        ss += v0 * asrc[h * C + 2 * c2] + v1 * asrc[h * C + 2 * c2 + 1];
        dd += v0 * adst[h * C + 2 * c2] + v1 * adst[h * C + 2 * c2 + 1];
    }
    s[tid] = ss; d[tid] = dd;
}

// ---- fused segment-softmax + aggregation + bias + relu ----
// One node per block, F/2 threads; thread t owns features (2t,2t+1): one dword
// (2xbf16) gather per edge. exp once per (edge,head) into LDS. No max pass
// (|e| <~ 6: fp32-safe; alpha mathematically identical).
template <int H, int C, bool OUT_BF16>
__global__ void k_agg(const ushortT* __restrict__ hb, const float* __restrict__ s,
                      const float* __restrict__ d, const int* __restrict__ offsets,
                      const int* __restrict__ csr_src, const float* __restrict__ bias,
                      void* __restrict__ xout) {
    static_assert(H == 4, "H=4 assumed for shift tricks");
    constexpr int F = H * C;
    constexpr int TPN = F / 2;   // threads per node
    constexpr int CHUNK = 256;
    __shared__ int lsrc[CHUNK];
    __shared__ float lex[CHUNK * H];
    __shared__ float ldn[H];
    int n = blockIdx.x;
    int t = threadIdx.x;          // 0..TPN-1
    int h = t / (C / 2);          // head of features 2t,2t+1
    int beg = offsets[n], end = offsets[n + 1];
    if (t < H) ldn[t] = d[n * H + t];

    const uintT* hbw = (const uintT*)hb;  // 2 bf16 per dword, row stride TPN dwords
    float sumex = 0.f, acc0 = 0.f, acc1 = 0.f;
    for (int base = beg; base < end; base += CHUNK) {
        int cnt = min(CHUNK, end - base);
        __syncthreads();
        for (int i = t; i < cnt; i += TPN) lsrc[i] = csr_src[base + i];
        for (int p = t; p < cnt * H; p += TPN) {
            int i = p >> 2;       // p / H
            int hp = p & 3;       // p % H
            int sn = csr_src[base + i];
            float e = s[sn * H + hp] + ldn[hp];
            e = e > 0.f ? e : 0.2f * e;
            lex[p] = __expf(e);
        }
        __syncthreads();
#pragma unroll 4
        for (int i = 0; i < cnt; i++) {
            int sn = lsrc[i];
            float ex = lex[i * H + h];
            sumex += ex;
            uintT w = hbw[(long)sn * TPN + t];
            acc0 += ex * bf_lo(w);
            acc1 += ex * bf_hi(w);
        }
    }
    float inv = 1.f / (sumex + 1e-16f);
    float o0 = fmaxf(acc0 * inv + bias[2 * t], 0.f);
    float o1 = fmaxf(acc1 * inv + bias[2 * t + 1], 0.f);
    if (OUT_BF16) {
        uintT pk = (uintT)f2bf(o0) | ((uintT)f2bf(o1) << 16);
        ((uintT*)xout)[(long)n * TPN + t] = pk;
    } else {
        float* xo = (float*)xout;
        xo[(long)n * F + 2 * t]     = o0;
        xo[(long)n * F + 2 * t + 1] = o1;
    }
}

// ---- graph boundaries via binary search on sorted batch ----
__global__ void k_bounds(const int* __restrict__ batch, int* __restrict__ bounds) {
    int g = threadIdx.x;  // 0..64
    if (g > N_GRAPHS) return;
    int lo = 0, hi = N_NODES;
    while (lo < hi) {
        int mid = (lo + hi) >> 1;
        if (batch[mid] < g) lo = mid + 1; else hi = mid;
    }
    bounds[g] = lo;
}

// ---- pool partials: block (g,s) sums a contiguous node slice, no atomics ----
__global__ void k_pool_partial(const float* __restrict__ x3, const int* __restrict__ bounds,
                               float* __restrict__ partial) {
    int g = blockIdx.x, s = blockIdx.y;
    int t = threadIdx.x;  // F2 threads
    int n0 = bounds[g], n1 = bounds[g + 1];
    int len = n1 - n0;
    int a = n0 + (int)((long)len * s / POOL_SPLITS);
    int b = n0 + (int)((long)len * (s + 1) / POOL_SPLITS);
    float acc = 0.f;
    for (int n = a; n < b; n++) acc += x3[(long)n * F2 + t];
    partial[((long)g * POOL_SPLITS + s) * F2 + t] = acc;
}

// ---- head: block per graph — reduce partials, mean, logits, softmax ----
__global__ void k_head(const float* __restrict__ partial, const int* __restrict__ bounds,
                       const float* __restrict__ Wout, const float* __restrict__ bout,
                       float* __restrict__ out) {
    __shared__ float red0[F2], red1[F2];
    int g = blockIdx.x;
    int t = threadIdx.x;  // F2 threads
    int cntN = bounds[g + 1] - bounds[g];
    float cnt = fmaxf((float)cntN, 1.0f);
    float sum = 0.f;
    for (int s = 0; s < POOL_SPLITS; s++)
        sum += partial[((long)g * POOL_SPLITS + s) * F2 + t];
    float p = sum / cnt;
    red0[t] = p * Wout[t * 2 + 0];
    red1[t] = p * Wout[t * 2 + 1];
    __syncthreads();
    for (int off = F2 / 2; off > 0; off >>= 1) {
        if (t < off) { red0[t] += red0[t + off]; red1[t] += red1[t + off]; }
        __syncthreads();
    }
    if (t == 0) {
        float l0 = red0[0] + bout[0];
        float l1 = red1[0] + bout[1];
        float m = fmaxf(l0, l1);
        float e0 = __expf(l0 - m), e1 = __expf(l1 - m);
        float inv = 1.f / (e0 + e1);
        out[g * 2 + 0] = e0 * inv;
        out[g * 2 + 1] = e1 * inv;
    }
}

extern "C" void kernel_launch(void* const* d_in, const int* in_sizes, int n_in,
                              void* d_out, int out_size, void* d_ws, size_t ws_size,
                              hipStream_t stream) {
    const float* x     = (const float*)d_in[0];
    const int*   ei    = (const int*)d_in[1];
    const int*   batch = (const int*)d_in[2];
    const float* W1    = (const float*)d_in[3];
    const float* asrc1 = (const float*)d_in[4];
    const float* adst1 = (const float*)d_in[5];
    const float* b1    = (const float*)d_in[6];
    const float* W2    = (const float*)d_in[7];
    const float* asrc2 = (const float*)d_in[8];
    const float* adst2 = (const float*)d_in[9];
    const float* b2    = (const float*)d_in[10];
    const float* Wout  = (const float*)d_in[11];
    const float* bout  = (const float*)d_in[12];

    char* ws = (char*)d_ws;
    size_t off = 0;
    auto alloc = [&](size_t bytes) -> void* {
        void* p = ws + off;
        off += (bytes + 255) / 256 * 256;
        return p;
    };
    ushortT* u_h   = (ushortT*)alloc(sizeof(ushortT) * (size_t)N_NODES * F1);  // bf16 h (both layers)
    ushortT* u_x1  = (ushortT*)alloc(sizeof(ushortT) * (size_t)N_NODES * F1);  // bf16 layer-1 agg out
    float*   f_x2  = (float*)alloc(sizeof(float) * (size_t)N_NODES * F2);      // fp32 layer-2 agg out
    float*   f_s   = (float*)alloc(sizeof(float) * (size_t)N_NODES * HEADS);
    float*   f_d   = (float*)alloc(sizeof(float) * (size_t)N_NODES * HEADS);
    int*     i_cnt = (int*)alloc(sizeof(int) * (size_t)N_NODES);
    int*     i_off = (int*)alloc(sizeof(int) * (size_t)(N_NODES + 1));
    int*     i_cur = (int*)alloc(sizeof(int) * (size_t)N_NODES);
    int*     i_csr = (int*)alloc(sizeof(int) * (size_t)ETOT);
    int*     i_bnd = (int*)alloc(sizeof(int) * (size_t)(N_GRAPHS + 1));
    float*   f_prt = (float*)alloc(sizeof(float) * (size_t)N_GRAPHS * POOL_SPLITS * F2);
    ushortT* pW1   = (ushortT*)alloc(sizeof(ushortT) * IN_CH * F1);
    ushortT* pW2   = (ushortT*)alloc(sizeof(ushortT) * F1 * F2);
    (void)ws_size; (void)in_sizes; (void)n_in; (void)out_size;

    hipMemsetAsync(i_cnt, 0, sizeof(int) * N_NODES, stream);
    hipMemsetAsync(i_cur, 0, sizeof(int) * N_NODES, stream);

    // CSR over dst (same for both layers)
    k_count<<<(ETOT + 255) / 256, 256, 0, stream>>>(ei, i_cnt);
    k_scan<<<1, 1024, 0, stream>>>(i_cnt, i_off);
    k_scatter<<<(ETOT + 255) / 256, 256, 0, stream>>>(ei, i_off, i_cur, i_csr);

    // Pack weights into MFMA B-fragment order (bf16)
    k_packW<IN_CH, F1><<<(IN_CH * F1 / 8 + 255) / 256, 256, 0, stream>>>(W1, pW1);
    k_packW<F1, F2><<<(F1 * F2 / 8 + 255) / 256, 256, 0, stream>>>(W2, pW2);

    int gemm_grid = (N_NODES + 63) / 64;

    // Layer 1
    k_gemm_mfma<IN_CH, F1, false><<<gemm_grid, 256, 0, stream>>>(x, (const uint4*)pW1, u_h, N_NODES);
    k_sd<HEADS, HID><<<(N_NODES * HEADS + 255) / 256, 256, 0, stream>>>(u_h, asrc1, adst1, f_s, f_d);
    k_agg<HEADS, HID, true><<<N_NODES, F1 / 2, 0, stream>>>(u_h, f_s, f_d, i_off, i_csr, b1, u_x1);

    // Layer 2
    k_gemm_mfma<F1, F2, true><<<gemm_grid, 256, 0, stream>>>(u_x1, (const uint4*)pW2, u_h, N_NODES);
    k_sd<HEADS, OUT_CH><<<(N_NODES * HEADS + 255) / 256, 256, 0, stream>>>(u_h, asrc2, adst2, f_s, f_d);
    k_agg<HEADS, OUT_CH, false><<<N_NODES, F2 / 2, 0, stream>>>(u_h, f_s, f_d, i_off, i_csr, b2, f_x2);

    // Pool + head (no atomics: batch is sorted -> contiguous graph ranges)
    k_bounds<<<1, N_GRAPHS + 1, 0, stream>>>(batch, i_bnd);
    dim3 pgrid(N_GRAPHS, POOL_SPLITS);
    k_pool_partial<<<pgrid, F2, 0, stream>>>(f_x2, i_bnd, f_prt);
    k_head<<<N_GRAPHS, F2, 0, stream>>>(f_prt, i_bnd, Wout, bout, (float*)d_out);
}

// Round 7
// 387.020 us; speedup vs baseline: 3.0560x; 1.1784x over previous
//
#include <hip/hip_runtime.h>
#include <hip/hip_bf16.h>

#define N_NODES 50000
#define N_EDGES 800000
#define ETOT (N_EDGES + N_NODES)
#define N_GRAPHS 64
#define HEADS 4
#define IN_CH 128
#define HID 64
#define F1 256  // HEADS*HID
#define OUT_CH 32
#define F2 128  // HEADS*OUT_CH
#define POOL_SPLITS 16
#define SCAN_B 256
#define SCAN_NB ((N_NODES + SCAN_B - 1) / SCAN_B)  // 196

typedef unsigned short ushortT;
typedef unsigned int uintT;
typedef short v8s __attribute__((ext_vector_type(8)));
typedef float v4f __attribute__((ext_vector_type(4)));

__device__ __forceinline__ ushortT f2bf(float f) {
    union { float f; unsigned int i; } v; v.f = f;
    unsigned int x = v.i;
    unsigned int r = (x + 0x7fffu + ((x >> 16) & 1u)) >> 16;  // RNE
    return (ushortT)r;
}
__device__ __forceinline__ float bf_lo(uintT w) {
    union { unsigned int i; float f; } v; v.i = w << 16; return v.f;
}
__device__ __forceinline__ float bf_hi(uintT w) {
    union { unsigned int i; float f; } v; v.i = w & 0xffff0000u; return v.f;
}

// ---- CSR build over dst (shared by both GAT layers) ----
__global__ void k_count(const int* __restrict__ ei, int* __restrict__ counts) {
    int e = blockIdx.x * blockDim.x + threadIdx.x;
    if (e >= ETOT) return;
    int dst = (e < N_EDGES) ? ei[N_EDGES + e] : (e - N_EDGES);
    atomicAdd(&counts[dst], 1);
}

// ---- parallel 3-phase exclusive scan (replaces 77us single-block scan) ----
__global__ void k_scan1(const int* __restrict__ counts, int* __restrict__ offs,
                        int* __restrict__ bsum) {
    __shared__ int sh[SCAN_B];
    int b = blockIdx.x, t = threadIdx.x;
    int i = b * SCAN_B + t;
    int v = (i < N_NODES) ? counts[i] : 0;
    sh[t] = v;
    __syncthreads();
    for (int o = 1; o < SCAN_B; o <<= 1) {
        int add = (t >= o) ? sh[t - o] : 0;
        __syncthreads();
        sh[t] += add;
        __syncthreads();
    }
    if (i < N_NODES) offs[i] = sh[t] - v;       // local exclusive
    if (t == SCAN_B - 1) bsum[b] = sh[t];       // block total
}

__global__ void k_scan2(const int* __restrict__ bsum, int* __restrict__ bbase,
                        int* __restrict__ offs) {
    __shared__ int sh[SCAN_B];
    int t = threadIdx.x;
    int v = (t < SCAN_NB) ? bsum[t] : 0;
    sh[t] = v;
    __syncthreads();
    for (int o = 1; o < SCAN_B; o <<= 1) {
        int add = (t >= o) ? sh[t - o] : 0;
        __syncthreads();
        sh[t] += add;
        __syncthreads();
    }
    if (t < SCAN_NB) bbase[t] = sh[t] - v;      // exclusive base per block
    if (t == SCAN_B - 1) offs[N_NODES] = sh[t]; // grand total (= ETOT)
}

__global__ void k_scan3(int* __restrict__ offs, const int* __restrict__ bbase) {
    int i = blockIdx.x * SCAN_B + threadIdx.x;
    if (i < N_NODES) offs[i] += bbase[blockIdx.x];
}

__global__ void k_scatter(const int* __restrict__ ei, const int* __restrict__ offsets,
                          int* __restrict__ cursor, int* __restrict__ csr_src) {
    int e = blockIdx.x * blockDim.x + threadIdx.x;
    if (e >= ETOT) return;
    int src, dst;
    if (e < N_EDGES) { src = ei[e]; dst = ei[N_EDGES + e]; }
    else             { src = dst = e - N_EDGES; }
    int pos = offsets[dst] + atomicAdd(&cursor[dst], 1);
    csr_src[pos] = src;
}

// ---- pack W (fp32 [K][N]) into bf16 B-fragment order for 16x16x32 MFMA ----
template <int FIN, int FOUT>
__global__ void k_packW(const float* __restrict__ W, ushortT* __restrict__ pW) {
    constexpr int KC = FIN / 32;
    int tid = blockIdx.x * blockDim.x + threadIdx.x;  // FIN*FOUT/8 threads
    if (tid >= FIN * FOUT / 8) return;
    int lane = tid & 63;
    int g = tid >> 6;
    int kc = g % KC, nt = g / KC;
    int n = nt * 16 + (lane & 15);
    int kbase = kc * 32 + (lane >> 4) * 8;
    union { uint4 q; ushortT u[8]; } pk;
#pragma unroll
    for (int j = 0; j < 8; j++) pk.u[j] = f2bf(W[(kbase + j) * FOUT + n]);
    ((uint4*)pW)[tid] = pk.q;
}

// ---- MFMA GEMM: out[r][n] = sum_k A[r][k]*W[k][n], bf16 out ----
template <int FIN, int FOUT, bool ABF16>
__global__ __launch_bounds__(256) void k_gemm_mfma(const void* __restrict__ A,
                                                   const uint4* __restrict__ Wp,
                                                   ushortT* __restrict__ out, int nrows) {
    constexpr int KC = FIN / 32;
    constexpr int NT = FOUT / 16;
    __shared__ uintT lW[FIN * FOUT / 2];  // 64 KB max
    int tid = threadIdx.x;
    uint4* lW4 = (uint4*)lW;
    for (int i = tid; i < FIN * FOUT * 2 / 16; i += 256) lW4[i] = Wp[i];
    __syncthreads();

    int wave = tid >> 6, lane = tid & 63;
    long row0 = (long)blockIdx.x * 64 + wave * 16;
    if (row0 >= nrows) return;  // wave-uniform (nrows % 16 == 0)
    int m = lane & 15, b = lane >> 4;

    v8s afrag[KC];
    if (ABF16) {
        const ushortT* Ab = (const ushortT*)A;
#pragma unroll
        for (int kc = 0; kc < KC; kc++) {
            union { v8s v; uint4 q; } u;
            u.q = *(const uint4*)(Ab + (row0 + m) * FIN + kc * 32 + b * 8);
            afrag[kc] = u.v;
        }
    } else {
        const float* Af = (const float*)A;
#pragma unroll
        for (int kc = 0; kc < KC; kc++) {
            union { v8s v; ushortT u[8]; } u;
            const float* p = Af + (row0 + m) * FIN + kc * 32 + b * 8;
#pragma unroll
            for (int j = 0; j < 8; j++) u.u[j] = f2bf(p[j]);
            afrag[kc] = u.v;
        }
    }

    const ushortT* lWs = (const ushortT*)lW;
#pragma unroll
    for (int nt = 0; nt < NT; nt++) {
        v4f c = {0.f, 0.f, 0.f, 0.f};
#pragma unroll
        for (int kc = 0; kc < KC; kc++) {
            union { v8s v; uint4 q; } bu;
            bu.q = *(const uint4*)(lWs + ((nt * KC + kc) * 64 + lane) * 8);
            c = __builtin_amdgcn_mfma_f32_16x16x32_bf16(afrag[kc], bu.v, c, 0, 0, 0);
        }
        // C/D: col = lane&15, row = (lane>>4)*4 + reg   [measured m89/m91]
        long r = row0 + b * 4;
        int col = nt * 16 + m;
#pragma unroll
        for (int reg = 0; reg < 4; reg++)
            out[(r + reg) * FOUT + col] = f2bf(c[reg]);
    }
}

// ---- per-node per-head attention terms s,d (bf16 h input) ----
template <int H, int C>
__global__ void k_sd(const ushortT* __restrict__ hb, const float* __restrict__ asrc,
                     const float* __restrict__ adst,
                     float* __restrict__ s, float* __restrict__ d) {
    int tid = blockIdx.x * blockDim.x + threadIdx.x;
    if (tid >= N_NODES * H) return;
    int n = tid / H, h = tid - n * H;
    const uintT* row = (const uintT*)(hb + (long)n * (H * C) + h * C);
    float ss = 0.f, dd = 0.f;
#pragma unroll 4
    for (int c2 = 0; c2 < C / 2; c2++) {
        uintT w = row[c2];
        float v0 = bf_lo(w), v1 = bf_hi(w);
        ss += v0 * asrc[h * C + 2 * c2] + v1 * asrc[h * C + 2 * c2 + 1];
        dd += v0 * adst[h * C + 2 * c2] + v1 * adst[h * C + 2 * c2 + 1];
    }
    s[tid] = ss; d[tid] = dd;
}

// ---- fused segment-softmax + aggregation + bias + relu ----
// One node per block, F/VEC threads; thread t owns VEC consecutive bf16
// features via one vectorized gather per edge. exp once per (edge,head) into
// LDS. No max pass (|e| <~ 6: fp32-safe; alpha mathematically identical).
template <int H, int C, int VEC, bool OUT_BF16>
__global__ void k_agg(const ushortT* __restrict__ hb, const float* __restrict__ s,
                      const float* __restrict__ d, const int* __restrict__ offsets,
                      const int* __restrict__ csr_src, const float* __restrict__ bias,
                      void* __restrict__ xout) {
    static_assert(H == 4, "H=4 assumed for shift tricks");
    static_assert(VEC == 2 || VEC == 4, "VEC in {2,4}");
    constexpr int F = H * C;
    constexpr int TPN = F / VEC;   // threads per node
    constexpr int CHUNK = 256;
    __shared__ int lsrc[CHUNK];
    __shared__ float lex[CHUNK * H];
    __shared__ float ldn[H];
    int n = blockIdx.x;
    int t = threadIdx.x;          // 0..TPN-1
    int h = t / (C / VEC);        // head of this thread's features
    int beg = offsets[n], end = offsets[n + 1];
    if (t < H) ldn[t] = d[n * H + t];

    float sumex = 0.f;
    float acc[VEC];
#pragma unroll
    for (int j = 0; j < VEC; j++) acc[j] = 0.f;

    for (int base = beg; base < end; base += CHUNK) {
        int cnt = min(CHUNK, end - base);
        __syncthreads();
        for (int i = t; i < cnt; i += TPN) lsrc[i] = csr_src[base + i];
        for (int p = t; p < cnt * H; p += TPN) {
            int i = p >> 2;       // p / H
            int hp = p & 3;       // p % H
            int sn = csr_src[base + i];
            float e = s[sn * H + hp] + ldn[hp];
            e = e > 0.f ? e : 0.2f * e;
            lex[p] = __expf(e);
        }
        __syncthreads();
        if (VEC == 4) {
            const uint2* hbw = (const uint2*)hb;
#pragma unroll 4
            for (int i = 0; i < cnt; i++) {
                int sn = lsrc[i];
                float ex = lex[i * H + h];
                sumex += ex;
                uint2 w = hbw[(long)sn * TPN + t];
                acc[0] += ex * bf_lo(w.x);
                acc[1] += ex * bf_hi(w.x);
                acc[2] += ex * bf_lo(w.y);
                acc[3] += ex * bf_hi(w.y);
            }
        } else {
            const uintT* hbw = (const uintT*)hb;
#pragma unroll 4
            for (int i = 0; i < cnt; i++) {
                int sn = lsrc[i];
                float ex = lex[i * H + h];
                sumex += ex;
                uintT w = hbw[(long)sn * TPN + t];
                acc[0] += ex * bf_lo(w);
                acc[1] += ex * bf_hi(w);
            }
        }
    }
    float inv = 1.f / (sumex + 1e-16f);
    float o[VEC];
#pragma unroll
    for (int j = 0; j < VEC; j++)
        o[j] = fmaxf(acc[j] * inv + bias[t * VEC + j], 0.f);
    if (OUT_BF16) {
        if (VEC == 4) {
            uint2 pk;
            pk.x = (uintT)f2bf(o[0]) | ((uintT)f2bf(o[1]) << 16);
            pk.y = (uintT)f2bf(o[2]) | ((uintT)f2bf(o[3]) << 16);
            ((uint2*)xout)[(long)n * TPN + t] = pk;
        } else {
            uintT pk = (uintT)f2bf(o[0]) | ((uintT)f2bf(o[1]) << 16);
            ((uintT*)xout)[(long)n * TPN + t] = pk;
        }
    } else {
        float* xo = (float*)xout;
#pragma unroll
        for (int j = 0; j < VEC; j++) xo[(long)n * F + t * VEC + j] = o[j];
    }
}

// ---- graph boundaries via binary search on sorted batch ----
__global__ void k_bounds(const int* __restrict__ batch, int* __restrict__ bounds) {
    int g = threadIdx.x;  // 0..64
    if (g > N_GRAPHS) return;
    int lo = 0, hi = N_NODES;
    while (lo < hi) {
        int mid = (lo + hi) >> 1;
        if (batch[mid] < g) lo = mid + 1; else hi = mid;
    }
    bounds[g] = lo;
}

// ---- pool partials: block (g,s) sums a contiguous node slice, no atomics ----
__global__ void k_pool_partial(const float* __restrict__ x3, const int* __restrict__ bounds,
                               float* __restrict__ partial) {
    int g = blockIdx.x, s = blockIdx.y;
    int t = threadIdx.x;  // F2 threads
    int n0 = bounds[g], n1 = bounds[g + 1];
    int len = n1 - n0;
    int a = n0 + (int)((long)len * s / POOL_SPLITS);
    int b = n0 + (int)((long)len * (s + 1) / POOL_SPLITS);
    float acc = 0.f;
    for (int n = a; n < b; n++) acc += x3[(long)n * F2 + t];
    partial[((long)g * POOL_SPLITS + s) * F2 + t] = acc;
}

// ---- head: block per graph — reduce partials, mean, logits, softmax ----
__global__ void k_head(const float* __restrict__ partial, const int* __restrict__ bounds,
                       const float* __restrict__ Wout, const float* __restrict__ bout,
                       float* __restrict__ out) {
    __shared__ float red0[F2], red1[F2];
    int g = blockIdx.x;
    int t = threadIdx.x;  // F2 threads
    int cntN = bounds[g + 1] - bounds[g];
    float cnt = fmaxf((float)cntN, 1.0f);
    float sum = 0.f;
    for (int s = 0; s < POOL_SPLITS; s++)
        sum += partial[((long)g * POOL_SPLITS + s) * F2 + t];
    float p = sum / cnt;
    red0[t] = p * Wout[t * 2 + 0];
    red1[t] = p * Wout[t * 2 + 1];
    __syncthreads();
    for (int off = F2 / 2; off > 0; off >>= 1) {
        if (t < off) { red0[t] += red0[t + off]; red1[t] += red1[t + off]; }
        __syncthreads();
    }
    if (t == 0) {
        float l0 = red0[0] + bout[0];
        float l1 = red1[0] + bout[1];
        float m = fmaxf(l0, l1);
        float e0 = __expf(l0 - m), e1 = __expf(l1 - m);
        float inv = 1.f / (e0 + e1);
        out[g * 2 + 0] = e0 * inv;
        out[g * 2 + 1] = e1 * inv;
    }
}

extern "C" void kernel_launch(void* const* d_in, const int* in_sizes, int n_in,
                              void* d_out, int out_size, void* d_ws, size_t ws_size,
                              hipStream_t stream) {
    const float* x     = (const float*)d_in[0];
    const int*   ei    = (const int*)d_in[1];
    const int*   batch = (const int*)d_in[2];
    const float* W1    = (const float*)d_in[3];
    const float* asrc1 = (const float*)d_in[4];
    const float* adst1 = (const float*)d_in[5];
    const float* b1    = (const float*)d_in[6];
    const float* W2    = (const float*)d_in[7];
    const float* asrc2 = (const float*)d_in[8];
    const float* adst2 = (const float*)d_in[9];
    const float* b2    = (const float*)d_in[10];
    const float* Wout  = (const float*)d_in[11];
    const float* bout  = (const float*)d_in[12];

    char* ws = (char*)d_ws;
    size_t off = 0;
    auto alloc = [&](size_t bytes) -> void* {
        void* p = ws + off;
        off += (bytes + 255) / 256 * 256;
        return p;
    };
    ushortT* u_h   = (ushortT*)alloc(sizeof(ushortT) * (size_t)N_NODES * F1);  // bf16 h (both layers)
    ushortT* u_x1  = (ushortT*)alloc(sizeof(ushortT) * (size_t)N_NODES * F1);  // bf16 layer-1 agg out
    float*   f_x2  = (float*)alloc(sizeof(float) * (size_t)N_NODES * F2);      // fp32 layer-2 agg out
    float*   f_s   = (float*)alloc(sizeof(float) * (size_t)N_NODES * HEADS);
    float*   f_d   = (float*)alloc(sizeof(float) * (size_t)N_NODES * HEADS);
    int*     i_cnt = (int*)alloc(sizeof(int) * (size_t)N_NODES);
    int*     i_off = (int*)alloc(sizeof(int) * (size_t)(N_NODES + 1));
    int*     i_cur = (int*)alloc(sizeof(int) * (size_t)N_NODES);
    int*     i_csr = (int*)alloc(sizeof(int) * (size_t)ETOT);
    int*     i_bnd = (int*)alloc(sizeof(int) * (size_t)(N_GRAPHS + 1));
    int*     i_bs  = (int*)alloc(sizeof(int) * SCAN_NB);
    int*     i_bb  = (int*)alloc(sizeof(int) * SCAN_NB);
    float*   f_prt = (float*)alloc(sizeof(float) * (size_t)N_GRAPHS * POOL_SPLITS * F2);
    ushortT* pW1   = (ushortT*)alloc(sizeof(ushortT) * IN_CH * F1);
    ushortT* pW2   = (ushortT*)alloc(sizeof(ushortT) * F1 * F2);
    (void)ws_size; (void)in_sizes; (void)n_in; (void)out_size;

    hipMemsetAsync(i_cnt, 0, sizeof(int) * N_NODES, stream);
    hipMemsetAsync(i_cur, 0, sizeof(int) * N_NODES, stream);

    // CSR over dst (same for both layers); 3-phase parallel exclusive scan
    k_count<<<(ETOT + 255) / 256, 256, 0, stream>>>(ei, i_cnt);
    k_scan1<<<SCAN_NB, SCAN_B, 0, stream>>>(i_cnt, i_off, i_bs);
    k_scan2<<<1, SCAN_B, 0, stream>>>(i_bs, i_bb, i_off);
    k_scan3<<<SCAN_NB, SCAN_B, 0, stream>>>(i_off, i_bb);
    k_scatter<<<(ETOT + 255) / 256, 256, 0, stream>>>(ei, i_off, i_cur, i_csr);

    // Pack weights into MFMA B-fragment order (bf16)
    k_packW<IN_CH, F1><<<(IN_CH * F1 / 8 + 255) / 256, 256, 0, stream>>>(W1, pW1);
    k_packW<F1, F2><<<(F1 * F2 / 8 + 255) / 256, 256, 0, stream>>>(W2, pW2);

    int gemm_grid = (N_NODES + 63) / 64;

    // Layer 1
    k_gemm_mfma<IN_CH, F1, false><<<gemm_grid, 256, 0, stream>>>(x, (const uint4*)pW1, u_h, N_NODES);
    k_sd<HEADS, HID><<<(N_NODES * HEADS + 255) / 256, 256, 0, stream>>>(u_h, asrc1, adst1, f_s, f_d);
    k_agg<HEADS, HID, 4, true><<<N_NODES, F1 / 4, 0, stream>>>(u_h, f_s, f_d, i_off, i_csr, b1, u_x1);

    // Layer 2
    k_gemm_mfma<F1, F2, true><<<gemm_grid, 256, 0, stream>>>(u_x1, (const uint4*)pW2, u_h, N_NODES);
    k_sd<HEADS, OUT_CH><<<(N_NODES * HEADS + 255) / 256, 256, 0, stream>>>(u_h, asrc2, adst2, f_s, f_d);
    k_agg<HEADS, OUT_CH, 2, false><<<N_NODES, F2 / 2, 0, stream>>>(u_h, f_s, f_d, i_off, i_csr, b2, f_x2);

    // Pool + head (no atomics: batch is sorted -> contiguous graph ranges)
    k_bounds<<<1, N_GRAPHS + 1, 0, stream>>>(batch, i_bnd);
    dim3 pgrid(N_GRAPHS, POOL_SPLITS);
    k_pool_partial<<<pgrid, F2, 0, stream>>>(f_x2, i_bnd, f_prt);
    k_head<<<N_GRAPHS, F2, 0, stream>>>(f_prt, i_bnd, Wout, bout, (float*)d_out);
}